// Round 5
// baseline (170.854 us; speedup 1.0000x reference)
//
#include <hip/hip_runtime.h>

// Problem constants: B=32, T=2048, H=512, f32 in/out.
#define BB 32
#define TT 2048
#define HH 512

#define NCHUNK 32                      // chunks (blocks) per batch
#define CHUNK (TT / NCHUNK)            // 64 rows per block
#define ROWS_PER_WAVE (CHUNK / 4)      // 16 (4 waves / 256-thread block)
#define PASSES (ROWS_PER_WAVE / 2)     // 8 (2 rows per pass, half-wave each)
#define PSTRIDE 516                    // floats per partial: 512 acc + Z + pad

__device__ __forceinline__ float dot4(float4 a, float4 b) {
  return a.x * b.x + a.y * b.y + a.z * b.z + a.w * b.w;
}

// ---------------------------------------------------------------------------
// Fused single-pass kernel. Streaming phase: identical layout to round 4
// (half-wave rows, no-max exp softmax, software-pipelined loads), but stores
// e = exp(s) into the weights buffer (normalized later). Each block writes a
// (acc[512], Z) partial, then release-fences and bumps its batch's counter.
// The 32nd (last) block of each batch acquire-fences and finalizes the batch:
// Z-merge, outputs[b,:], and in-place weights normalization — overlapping
// with other batches' streaming instead of a dependent second kernel.
// ---------------------------------------------------------------------------
__global__ __launch_bounds__(256) void fused_kernel(
    const float* __restrict__ in, const float* __restrict__ W,
    const float* __restrict__ bias, float* __restrict__ out,
    float* __restrict__ weights, float* __restrict__ partials,
    unsigned int* __restrict__ counters) {
  const int b    = blockIdx.x >> 5;             // / NCHUNK
  const int ch   = blockIdx.x & (NCHUNK - 1);
  const int wid  = threadIdx.x >> 6;            // 0..3
  const int lane = threadIdx.x & 63;
  const int h    = lane >> 5;                   // row parity within pass
  const int c    = lane & 31;                   // float4 column 0..31

  const float4* w4p = reinterpret_cast<const float4*>(W);
  const float4 w0 = w4p[c];
  const float4 w1 = w4p[c + 32];
  const float4 w2 = w4p[c + 64];
  const float4 w3 = w4p[c + 96];
  const float bs = bias[0];

  const int t0 = ch * CHUNK + wid * ROWS_PER_WAVE;
  const float4* rowbase = reinterpret_cast<const float4*>(in) +
                          ((size_t)b * TT + t0) * (HH / 4);
  float* ev = weights + (size_t)b * TT + t0;   // exp(s) staged here

  float4 acc[4];
  acc[0] = acc[1] = acc[2] = acc[3] = make_float4(0.f, 0.f, 0.f, 0.f);
  float Z = 0.f;

  float4 A[4], Bf[4];

#define LD(p, buf)                                                        \
  {                                                                       \
    const float4* rp = rowbase + (size_t)((p) * 2 + h) * (HH / 4) + c;    \
    buf[0] = rp[0];                                                       \
    buf[1] = rp[32];                                                      \
    buf[2] = rp[64];                                                      \
    buf[3] = rp[96];                                                      \
  }

#define PROC(p, buf)                                                      \
  {                                                                       \
    float s = dot4(buf[0], w0) + dot4(buf[1], w1) +                       \
              dot4(buf[2], w2) + dot4(buf[3], w3);                        \
    s += __shfl_xor(s, 1, 32);                                            \
    s += __shfl_xor(s, 2, 32);                                            \
    s += __shfl_xor(s, 4, 32);                                            \
    s += __shfl_xor(s, 8, 32);                                            \
    s += __shfl_xor(s, 16, 32);                                           \
    const float e = __expf(s + bs);                                       \
    if (c == 0) ev[(p) * 2 + h] = e;                                      \
    Z += e;                                                               \
    acc[0].x += e * buf[0].x; acc[0].y += e * buf[0].y;                   \
    acc[0].z += e * buf[0].z; acc[0].w += e * buf[0].w;                   \
    acc[1].x += e * buf[1].x; acc[1].y += e * buf[1].y;                   \
    acc[1].z += e * buf[1].z; acc[1].w += e * buf[1].w;                   \
    acc[2].x += e * buf[2].x; acc[2].y += e * buf[2].y;                   \
    acc[2].z += e * buf[2].z; acc[2].w += e * buf[2].w;                   \
    acc[3].x += e * buf[3].x; acc[3].y += e * buf[3].y;                   \
    acc[3].z += e * buf[3].z; acc[3].w += e * buf[3].w;                   \
  }

  // software pipeline: loads for pass p+1 issue before processing pass p
  LD(0, A);
#pragma unroll
  for (int p = 0; p < PASSES; p += 2) {
    if (p + 1 < PASSES) LD(p + 1, Bf);
    PROC(p, A);
    if (p + 2 < PASSES) LD(p + 2, A);
    if (p + 1 < PASSES) PROC(p + 1, Bf);
  }
#undef LD
#undef PROC

  // combine the two half-waves: lanes l and l^32 hold the same column slice
#pragma unroll
  for (int k = 0; k < 4; ++k) {
    acc[k].x += __shfl_xor(acc[k].x, 32);
    acc[k].y += __shfl_xor(acc[k].y, 32);
    acc[k].z += __shfl_xor(acc[k].z, 32);
    acc[k].w += __shfl_xor(acc[k].w, 32);
  }
  Z += __shfl_xor(Z, 32);

  // per-wave partial -> LDS
  __shared__ float4 sacc[4][128];  // 8 KB
  __shared__ float sZ[4];
  if (lane < 32) {
    sacc[wid][c]      = acc[0];
    sacc[wid][c + 32] = acc[1];
    sacc[wid][c + 64] = acc[2];
    sacc[wid][c + 96] = acc[3];
  }
  if (lane == 0) sZ[wid] = Z;
  __syncthreads();

  // block combine: 4 waves -> one partial record
  if (threadIdx.x < 128) {
    const int col = threadIdx.x;
    const float4 r0 = sacc[0][col], r1 = sacc[1][col];
    const float4 r2 = sacc[2][col], r3 = sacc[3][col];
    float4 r;
    r.x = (r0.x + r1.x) + (r2.x + r3.x);
    r.y = (r0.y + r1.y) + (r2.y + r3.y);
    r.z = (r0.z + r1.z) + (r2.z + r3.z);
    r.w = (r0.w + r1.w) + (r2.w + r3.w);
    float* p = partials + (size_t)blockIdx.x * PSTRIDE;
    reinterpret_cast<float4*>(p)[col] = r;
    if (col == 0) p[512] = (sZ[0] + sZ[1]) + (sZ[2] + sZ[3]);
  }

  // ---- publish partial, last block of this batch finalizes ----
  __threadfence();          // release: partials + ev stores visible device-wide
  __syncthreads();          // all waves' fences done before the atomic
  __shared__ int s_last;
  if (threadIdx.x == 0) {
    const unsigned int old = atomicAdd(&counters[b], 1u);
    s_last = (old == NCHUNK - 1) ? 1 : 0;
  }
  __syncthreads();
  if (s_last) {
    __threadfence();        // acquire: see all 32 blocks' partials + ev
    const float* pb = partials + (size_t)b * NCHUNK * PSTRIDE;

    float Zg = 0.f;
#pragma unroll
    for (int cc = 0; cc < NCHUNK; ++cc) Zg += pb[cc * PSTRIDE + 512];
    const float invZ = 1.f / Zg;

    if (threadIdx.x < 128) {
      float4 r = make_float4(0.f, 0.f, 0.f, 0.f);
#pragma unroll
      for (int cc = 0; cc < NCHUNK; ++cc) {
        const float4 a =
            reinterpret_cast<const float4*>(pb + cc * PSTRIDE)[threadIdx.x];
        r.x += a.x; r.y += a.y; r.z += a.z; r.w += a.w;
      }
      r.x *= invZ; r.y *= invZ; r.z *= invZ; r.w *= invZ;
      reinterpret_cast<float4*>(out + (size_t)b * HH)[threadIdx.x] = r;
    }

    // weights: w = e / Z, in place (512 float4 / 256 threads = 2 each)
    float4* wv = reinterpret_cast<float4*>(weights + (size_t)b * TT);
#pragma unroll
    for (int i = threadIdx.x; i < TT / 4; i += 256) {
      float4 v = wv[i];
      v.x *= invZ; v.y *= invZ; v.z *= invZ; v.w *= invZ;
      wv[i] = v;
    }
  }
}

extern "C" void kernel_launch(void* const* d_in, const int* in_sizes, int n_in,
                              void* d_out, int out_size, void* d_ws, size_t ws_size,
                              hipStream_t stream) {
  const float* in   = (const float*)d_in[0];  // [B,T,H]
  const float* W    = (const float*)d_in[1];  // [H,1]
  const float* bias = (const float*)d_in[2];  // [1]

  float* out     = (float*)d_out;        // outputs [B,H]
  float* weights = out + BB * HH;        // attention_weights [B,T,1]

  float* partials = (float*)d_ws;        // BB*NCHUNK*PSTRIDE f32 ≈ 2.1 MB
  unsigned int* counters = (unsigned int*)((char*)d_ws +
      (size_t)BB * NCHUNK * PSTRIDE * sizeof(float));

  hipMemsetAsync(counters, 0, BB * sizeof(unsigned int), stream);
  fused_kernel<<<BB * NCHUNK, 256, 0, stream>>>(in, W, bias, out, weights,
                                                partials, counters);
}

// Round 6
// 34.943 us; speedup vs baseline: 4.8894x; 4.8894x over previous
//
#include <hip/hip_runtime.h>

// Problem constants: B=32, T=2048, H=512, f32 in/out.
#define BB 32
#define TT 2048
#define HH 512
#define PSTRIDE 516   // floats per partial record: 512 acc + Z + pad

__device__ __forceinline__ float dot4(float4 a, float4 b) {
  return a.x * b.x + a.y * b.y + a.z * b.z + a.w * b.w;
}

// ---------------------------------------------------------------------------
// Pass 1 (single read of the input). No-max softmax (scores ~ N(0,1), f32
// exp is overflow-safe; softmax is shift-invariant). Half-wave row layout:
// lane l -> row parity h=l>>5, float4 col c=l&31. Per pass (2 rows):
// 4 prefetched float4 loads/lane, 16-FMA partial dot, 5-step butterfly in
// 32 lanes, exp, 16 independent accum FMAs. Stores e=exp(s+b) to the
// weights buffer (normalized by finalize). Depth-2 software pipeline.
// NC = chunks per batch (template; 64 rows/chunk at NC=32, 32 at NC=64).
// ---------------------------------------------------------------------------
template <int NC>
__global__ __launch_bounds__(256) void pass1_kernel(
    const float* __restrict__ in, const float* __restrict__ W,
    const float* __restrict__ bias, float* __restrict__ weights,
    float* __restrict__ partials) {
  constexpr int CHUNK = TT / NC;
  constexpr int RPW = CHUNK / 4;      // rows per wave
  constexpr int PASSES = RPW / 2;     // 2 rows per pass

  const int b    = blockIdx.x / NC;
  const int ch   = blockIdx.x % NC;
  const int wid  = threadIdx.x >> 6;  // 0..3
  const int lane = threadIdx.x & 63;
  const int h    = lane >> 5;         // row parity within pass
  const int c    = lane & 31;         // float4 column 0..31

  const float4* w4p = reinterpret_cast<const float4*>(W);
  const float4 w0 = w4p[c];
  const float4 w1 = w4p[c + 32];
  const float4 w2 = w4p[c + 64];
  const float4 w3 = w4p[c + 96];
  const float bs = bias[0];

  const int t0 = ch * CHUNK + wid * RPW;
  const float4* rowbase = reinterpret_cast<const float4*>(in) +
                          ((size_t)b * TT + t0) * (HH / 4);
  float* ev = weights + (size_t)b * TT + t0;  // e staged here

  float4 acc[4];
  acc[0] = acc[1] = acc[2] = acc[3] = make_float4(0.f, 0.f, 0.f, 0.f);
  float Z = 0.f;

  float4 A[4], Bf[4];

#define LD(p, buf)                                                        \
  {                                                                       \
    const float4* rp = rowbase + (size_t)((p) * 2 + h) * (HH / 4) + c;    \
    buf[0] = rp[0];                                                       \
    buf[1] = rp[32];                                                      \
    buf[2] = rp[64];                                                      \
    buf[3] = rp[96];                                                      \
  }

#define PROC(p, buf)                                                      \
  {                                                                       \
    float s = dot4(buf[0], w0) + dot4(buf[1], w1) +                       \
              dot4(buf[2], w2) + dot4(buf[3], w3);                        \
    s += __shfl_xor(s, 1, 32);                                            \
    s += __shfl_xor(s, 2, 32);                                            \
    s += __shfl_xor(s, 4, 32);                                            \
    s += __shfl_xor(s, 8, 32);                                            \
    s += __shfl_xor(s, 16, 32);                                           \
    const float e = __expf(s + bs);                                       \
    if (c == 0) ev[(p) * 2 + h] = e;                                      \
    Z += e;                                                               \
    acc[0].x += e * buf[0].x; acc[0].y += e * buf[0].y;                   \
    acc[0].z += e * buf[0].z; acc[0].w += e * buf[0].w;                   \
    acc[1].x += e * buf[1].x; acc[1].y += e * buf[1].y;                   \
    acc[1].z += e * buf[1].z; acc[1].w += e * buf[1].w;                   \
    acc[2].x += e * buf[2].x; acc[2].y += e * buf[2].y;                   \
    acc[2].z += e * buf[2].z; acc[2].w += e * buf[2].w;                   \
    acc[3].x += e * buf[3].x; acc[3].y += e * buf[3].y;                   \
    acc[3].z += e * buf[3].z; acc[3].w += e * buf[3].w;                   \
  }

  LD(0, A);
#pragma unroll
  for (int p = 0; p < PASSES; p += 2) {
    if (p + 1 < PASSES) LD(p + 1, Bf);
    PROC(p, A);
    if (p + 2 < PASSES) LD(p + 2, A);
    if (p + 1 < PASSES) PROC(p + 1, Bf);
  }
#undef LD
#undef PROC

  // combine the two half-waves (lanes l and l^32 hold the same column slice)
#pragma unroll
  for (int k = 0; k < 4; ++k) {
    acc[k].x += __shfl_xor(acc[k].x, 32);
    acc[k].y += __shfl_xor(acc[k].y, 32);
    acc[k].z += __shfl_xor(acc[k].z, 32);
    acc[k].w += __shfl_xor(acc[k].w, 32);
  }
  Z += __shfl_xor(Z, 32);

  // per-wave partial -> LDS, block combine -> one partial record
  __shared__ float4 sacc[4][128];  // 8 KB
  __shared__ float sZ[4];
  if (lane < 32) {
    sacc[wid][c]      = acc[0];
    sacc[wid][c + 32] = acc[1];
    sacc[wid][c + 64] = acc[2];
    sacc[wid][c + 96] = acc[3];
  }
  if (lane == 0) sZ[wid] = Z;
  __syncthreads();

  if (threadIdx.x < 128) {
    const int col = threadIdx.x;
    const float4 r0 = sacc[0][col], r1 = sacc[1][col];
    const float4 r2 = sacc[2][col], r3 = sacc[3][col];
    float4 r;
    r.x = (r0.x + r1.x) + (r2.x + r3.x);
    r.y = (r0.y + r1.y) + (r2.y + r3.y);
    r.z = (r0.z + r1.z) + (r2.z + r3.z);
    r.w = (r0.w + r1.w) + (r2.w + r3.w);
    float* p = partials + (size_t)blockIdx.x * PSTRIDE;
    reinterpret_cast<float4*>(p)[col] = r;
    if (col == 0) p[512] = (sZ[0] + sZ[1]) + (sZ[2] + sZ[3]);
  }
}

// ---------------------------------------------------------------------------
// Pass 2 (tiny, 2 blocks per batch): slice 0 merges partials -> outputs[b,:];
// slice 1 normalizes the staged e values -> attention weights. Both slices
// redundantly compute Z from the NC partial Z's (L2-hit scalar reads).
// ---------------------------------------------------------------------------
template <int NC>
__global__ __launch_bounds__(512) void finalize_kernel(
    const float* __restrict__ partials, float* __restrict__ weights,
    float* __restrict__ out) {
  const int b     = blockIdx.x >> 1;
  const int slice = blockIdx.x & 1;
  const int tid   = threadIdx.x;
  const float* pb = partials + (size_t)b * NC * PSTRIDE;

  float Zg = 0.f;
#pragma unroll
  for (int cc = 0; cc < NC; ++cc) Zg += pb[cc * PSTRIDE + 512];
  const float invZ = 1.f / Zg;

  if (slice == 0) {
    // outputs: 128 float4 columns x 4 partial-groups, LDS tree
    const int col = tid & 127;
    const int g   = tid >> 7;  // 0..3
    float4 r = make_float4(0.f, 0.f, 0.f, 0.f);
#pragma unroll
    for (int cc = g; cc < NC; cc += 4) {
      const float4 a = reinterpret_cast<const float4*>(pb + cc * PSTRIDE)[col];
      r.x += a.x; r.y += a.y; r.z += a.z; r.w += a.w;
    }
    __shared__ float4 red[512];
    red[tid] = r;
    __syncthreads();
    if (tid < 128) {
      const float4 a0 = red[tid], a1 = red[tid + 128];
      const float4 a2 = red[tid + 256], a3 = red[tid + 384];
      float4 o;
      o.x = ((a0.x + a1.x) + (a2.x + a3.x)) * invZ;
      o.y = ((a0.y + a1.y) + (a2.y + a3.y)) * invZ;
      o.z = ((a0.z + a1.z) + (a2.z + a3.z)) * invZ;
      o.w = ((a0.w + a1.w) + (a2.w + a3.w)) * invZ;
      reinterpret_cast<float4*>(out + (size_t)b * HH)[tid] = o;
    }
  } else {
    // weights: w = e * invZ, one float4 per thread (512 x 4 = 2048 = TT)
    float4* wv = reinterpret_cast<float4*>(weights + (size_t)b * TT);
    float4 v = wv[tid];
    v.x *= invZ; v.y *= invZ; v.z *= invZ; v.w *= invZ;
    wv[tid] = v;
  }
}

extern "C" void kernel_launch(void* const* d_in, const int* in_sizes, int n_in,
                              void* d_out, int out_size, void* d_ws, size_t ws_size,
                              hipStream_t stream) {
  const float* in   = (const float*)d_in[0];  // [B,T,H]
  const float* W    = (const float*)d_in[1];  // [H,1]
  const float* bias = (const float*)d_in[2];  // [1]

  float* out      = (float*)d_out;   // outputs [B,H]
  float* weights  = out + BB * HH;   // attention_weights [B,T,1]
  float* partials = (float*)d_ws;

  const size_t need64 = (size_t)BB * 64 * PSTRIDE * sizeof(float);  // ~4.2 MB
  if (ws_size >= need64) {
    pass1_kernel<64><<<BB * 64, 256, 0, stream>>>(in, W, bias, weights, partials);
    finalize_kernel<64><<<BB * 2, 512, 0, stream>>>(partials, weights, out);
  } else {
    pass1_kernel<32><<<BB * 32, 256, 0, stream>>>(in, W, bias, weights, partials);
    finalize_kernel<32><<<BB * 2, 512, 0, stream>>>(partials, weights, out);
  }
}

// Round 7
// 30.619 us; speedup vs baseline: 5.5800x; 1.1412x over previous
//
#include <hip/hip_runtime.h>

// Problem constants: B=32, T=2048, H=512, f32 in/out.
#define BB 32
#define TT 2048
#define HH 512

#define NC 16                      // chunks per batch
#define CHUNK (TT / NC)            // 128 rows per block
#define RPW (CHUNK / 4)            // 32 rows per wave
#define PASSES (RPW / 2)           // 16 (2 rows per pass, half-wave each)
#define PREC 512                   // floats per partial record (acc only)

__device__ __forceinline__ float dot4(float4 a, float4 b) {
  return a.x * b.x + a.y * b.y + a.z * b.z + a.w * b.w;
}

// ---------------------------------------------------------------------------
// Pass 1 (single read of the input). No-max softmax (scores ~ N(0,1); f32
// exp overflow-safe; softmax shift-invariant). Half-wave row layout: lane l
// -> row parity h=l>>5, float4 col c=l&31. Per pass (2 rows): 4 prefetched
// float4 loads/lane, 16-FMA partial dot, 5-step butterfly in 32 lanes, exp,
// 16 independent accum FMAs. Stores e=exp(s+b) to the weights buffer.
// Depth-2 software pipeline over 16 passes (long loop amortizes fill/drain
// and per-block prologue/epilogue — R6 lesson: fewer, longer blocks win).
// ---------------------------------------------------------------------------
__global__ __launch_bounds__(256) void pass1_kernel(
    const float* __restrict__ in, const float* __restrict__ W,
    const float* __restrict__ bias, float* __restrict__ weights,
    float* __restrict__ partials, float* __restrict__ zarr) {
  const int b    = blockIdx.x >> 4;             // / NC
  const int ch   = blockIdx.x & (NC - 1);
  const int wid  = threadIdx.x >> 6;            // 0..3
  const int lane = threadIdx.x & 63;
  const int h    = lane >> 5;                   // row parity within pass
  const int c    = lane & 31;                   // float4 column 0..31

  const float4* w4p = reinterpret_cast<const float4*>(W);
  const float4 w0 = w4p[c];
  const float4 w1 = w4p[c + 32];
  const float4 w2 = w4p[c + 64];
  const float4 w3 = w4p[c + 96];
  const float bs = bias[0];

  const int t0 = ch * CHUNK + wid * RPW;
  const float4* rowbase = reinterpret_cast<const float4*>(in) +
                          ((size_t)b * TT + t0) * (HH / 4);
  float* ev = weights + (size_t)b * TT + t0;  // e staged here

  float4 acc[4];
  acc[0] = acc[1] = acc[2] = acc[3] = make_float4(0.f, 0.f, 0.f, 0.f);
  float Z = 0.f;

  float4 A[4], Bf[4];

#define LD(p, buf)                                                        \
  {                                                                       \
    const float4* rp = rowbase + (size_t)((p) * 2 + h) * (HH / 4) + c;    \
    buf[0] = rp[0];                                                       \
    buf[1] = rp[32];                                                      \
    buf[2] = rp[64];                                                      \
    buf[3] = rp[96];                                                      \
  }

#define PROC(p, buf)                                                      \
  {                                                                       \
    float s = dot4(buf[0], w0) + dot4(buf[1], w1) +                       \
              dot4(buf[2], w2) + dot4(buf[3], w3);                        \
    s += __shfl_xor(s, 1, 32);                                            \
    s += __shfl_xor(s, 2, 32);                                            \
    s += __shfl_xor(s, 4, 32);                                            \
    s += __shfl_xor(s, 8, 32);                                            \
    s += __shfl_xor(s, 16, 32);                                           \
    const float e = __expf(s + bs);                                       \
    if (c == 0) ev[(p) * 2 + h] = e;                                      \
    Z += e;                                                               \
    acc[0].x += e * buf[0].x; acc[0].y += e * buf[0].y;                   \
    acc[0].z += e * buf[0].z; acc[0].w += e * buf[0].w;                   \
    acc[1].x += e * buf[1].x; acc[1].y += e * buf[1].y;                   \
    acc[1].z += e * buf[1].z; acc[1].w += e * buf[1].w;                   \
    acc[2].x += e * buf[2].x; acc[2].y += e * buf[2].y;                   \
    acc[2].z += e * buf[2].z; acc[2].w += e * buf[2].w;                   \
    acc[3].x += e * buf[3].x; acc[3].y += e * buf[3].y;                   \
    acc[3].z += e * buf[3].z; acc[3].w += e * buf[3].w;                   \
  }

  LD(0, A);
#pragma unroll
  for (int p = 0; p < PASSES; p += 2) {
    if (p + 1 < PASSES) LD(p + 1, Bf);
    PROC(p, A);
    if (p + 2 < PASSES) LD(p + 2, A);
    if (p + 1 < PASSES) PROC(p + 1, Bf);
  }
#undef LD
#undef PROC

  // combine the two half-waves (lanes l and l^32 hold the same column slice)
#pragma unroll
  for (int k = 0; k < 4; ++k) {
    acc[k].x += __shfl_xor(acc[k].x, 32);
    acc[k].y += __shfl_xor(acc[k].y, 32);
    acc[k].z += __shfl_xor(acc[k].z, 32);
    acc[k].w += __shfl_xor(acc[k].w, 32);
  }
  Z += __shfl_xor(Z, 32);

  // per-wave partial -> LDS, block combine -> one partial record + compact Z
  __shared__ float4 sacc[4][128];  // 8 KB
  __shared__ float sZ[4];
  if (lane < 32) {
    sacc[wid][c]      = acc[0];
    sacc[wid][c + 32] = acc[1];
    sacc[wid][c + 64] = acc[2];
    sacc[wid][c + 96] = acc[3];
  }
  if (lane == 0) sZ[wid] = Z;
  __syncthreads();

  if (threadIdx.x < 128) {
    const int col = threadIdx.x;
    const float4 r0 = sacc[0][col], r1 = sacc[1][col];
    const float4 r2 = sacc[2][col], r3 = sacc[3][col];
    float4 r;
    r.x = (r0.x + r1.x) + (r2.x + r3.x);
    r.y = (r0.y + r1.y) + (r2.y + r3.y);
    r.z = (r0.z + r1.z) + (r2.z + r3.z);
    r.w = (r0.w + r1.w) + (r2.w + r3.w);
    reinterpret_cast<float4*>(partials + (size_t)blockIdx.x * PREC)[col] = r;
    if (col == 0) zarr[blockIdx.x] = (sZ[0] + sZ[1]) + (sZ[2] + sZ[3]);
  }
}

// ---------------------------------------------------------------------------
// Pass 2 (tiny, 2 blocks per batch): slice 0 merges the NC acc-partials ->
// outputs[b,:]; slice 1 normalizes staged e -> attention weights. Z comes
// from one contiguous 64 B cacheline per batch.
// ---------------------------------------------------------------------------
__global__ __launch_bounds__(512) void finalize_kernel(
    const float* __restrict__ partials, const float* __restrict__ zarr,
    float* __restrict__ weights, float* __restrict__ out) {
  const int b     = blockIdx.x >> 1;
  const int slice = blockIdx.x & 1;
  const int tid   = threadIdx.x;

  const float* zb = zarr + b * NC;
  float Zg = 0.f;
#pragma unroll
  for (int cc = 0; cc < NC; ++cc) Zg += zb[cc];
  const float invZ = 1.f / Zg;

  if (slice == 0) {
    // outputs: 128 float4 columns x 4 partial-groups, LDS tree
    const float* pb = partials + (size_t)b * NC * PREC;
    const int col = tid & 127;
    const int g   = tid >> 7;  // 0..3 -> records g, g+4, g+8, g+12
    float4 r = make_float4(0.f, 0.f, 0.f, 0.f);
#pragma unroll
    for (int cc = g; cc < NC; cc += 4) {
      const float4 a = reinterpret_cast<const float4*>(pb + cc * PREC)[col];
      r.x += a.x; r.y += a.y; r.z += a.z; r.w += a.w;
    }
    __shared__ float4 red[512];
    red[tid] = r;
    __syncthreads();
    if (tid < 128) {
      const float4 a0 = red[tid], a1 = red[tid + 128];
      const float4 a2 = red[tid + 256], a3 = red[tid + 384];
      float4 o;
      o.x = ((a0.x + a1.x) + (a2.x + a3.x)) * invZ;
      o.y = ((a0.y + a1.y) + (a2.y + a3.y)) * invZ;
      o.z = ((a0.z + a1.z) + (a2.z + a3.z)) * invZ;
      o.w = ((a0.w + a1.w) + (a2.w + a3.w)) * invZ;
      reinterpret_cast<float4*>(out + (size_t)b * HH)[tid] = o;
    }
  } else {
    // weights: w = e * invZ, one float4 per thread (512 x 4 = 2048 = TT)
    float4* wv = reinterpret_cast<float4*>(weights + (size_t)b * TT);
    float4 v = wv[tid];
    v.x *= invZ; v.y *= invZ; v.z *= invZ; v.w *= invZ;
    wv[tid] = v;
  }
}

extern "C" void kernel_launch(void* const* d_in, const int* in_sizes, int n_in,
                              void* d_out, int out_size, void* d_ws, size_t ws_size,
                              hipStream_t stream) {
  const float* in   = (const float*)d_in[0];  // [B,T,H]
  const float* W    = (const float*)d_in[1];  // [H,1]
  const float* bias = (const float*)d_in[2];  // [1]

  float* out      = (float*)d_out;   // outputs [B,H]
  float* weights  = out + BB * HH;   // attention_weights [B,T,1]

  float* partials = (float*)d_ws;                       // 512*512*4 = 1 MB
  float* zarr     = partials + (size_t)BB * NC * PREC;  // 512 floats

  pass1_kernel<<<BB * NC, 256, 0, stream>>>(in, W, bias, weights, partials, zarr);
  finalize_kernel<<<BB * 2, 512, 0, stream>>>(partials, zarr, weights, out);
}

// Round 8
// 29.200 us; speedup vs baseline: 5.8512x; 1.0486x over previous
//
#include <hip/hip_runtime.h>

// Problem constants: B=32, T=2048, H=512, f32 in/out.
#define BB 32
#define TT 2048
#define HH 512

#define NC 32                      // chunks per batch (measured best: R4)
#define CHUNK (TT / NC)            // 64 rows per block
#define RPW (CHUNK / 4)            // 16 rows per wave
#define PASSES (RPW / 2)           // 8 (2 rows per pass, half-wave each)
#define PREC 512                   // floats per partial record (acc only)

__device__ __forceinline__ float dot4(float4 a, float4 b) {
  return a.x * b.x + a.y * b.y + a.z * b.z + a.w * b.w;
}

// ---------------------------------------------------------------------------
// Pass 1 (single read of the input). No-max softmax (scores ~ N(0,1); f32
// exp overflow-safe; softmax shift-invariant). Half-wave row layout: lane l
// -> row parity h=l>>5, float4 col c=l&31. Per pass (2 rows): 4 float4
// loads/lane, 16-FMA partial dot, 5-step butterfly in 32 lanes, exp, 16
// independent accum FMAs. Stores e=exp(s+b) to the weights buffer.
// Depth-3 rotating-buffer pipeline: 2 LD batches (8 loads) always in
// flight ahead of the PROC consuming the third — covers ~900cyc HBM
// latency better than R4's 1-ahead scheme at 4 waves/SIMD.
// ---------------------------------------------------------------------------
__global__ __launch_bounds__(256) void pass1_kernel(
    const float* __restrict__ in, const float* __restrict__ W,
    const float* __restrict__ bias, float* __restrict__ weights,
    float* __restrict__ partials, float* __restrict__ zarr) {
  const int b    = blockIdx.x >> 5;             // / NC
  const int ch   = blockIdx.x & (NC - 1);
  const int wid  = threadIdx.x >> 6;            // 0..3
  const int lane = threadIdx.x & 63;
  const int h    = lane >> 5;                   // row parity within pass
  const int c    = lane & 31;                   // float4 column 0..31

  const float4* w4p = reinterpret_cast<const float4*>(W);
  const float4 w0 = w4p[c];
  const float4 w1 = w4p[c + 32];
  const float4 w2 = w4p[c + 64];
  const float4 w3 = w4p[c + 96];
  const float bs = bias[0];

  const int t0 = ch * CHUNK + wid * RPW;
  const float4* rowbase = reinterpret_cast<const float4*>(in) +
                          ((size_t)b * TT + t0) * (HH / 4);
  float* ev = weights + (size_t)b * TT + t0;  // e staged here

  float4 acc[4];
  acc[0] = acc[1] = acc[2] = acc[3] = make_float4(0.f, 0.f, 0.f, 0.f);
  float Z = 0.f;

  float4 A[4], Bf[4], Cf[4];

#define LD(p, buf)                                                        \
  {                                                                       \
    const float4* rp = rowbase + (size_t)((p) * 2 + h) * (HH / 4) + c;    \
    buf[0] = rp[0];                                                       \
    buf[1] = rp[32];                                                      \
    buf[2] = rp[64];                                                      \
    buf[3] = rp[96];                                                      \
  }

#define PROC(p, buf)                                                      \
  {                                                                       \
    float s = dot4(buf[0], w0) + dot4(buf[1], w1) +                       \
              dot4(buf[2], w2) + dot4(buf[3], w3);                        \
    s += __shfl_xor(s, 1, 32);                                            \
    s += __shfl_xor(s, 2, 32);                                            \
    s += __shfl_xor(s, 4, 32);                                            \
    s += __shfl_xor(s, 8, 32);                                            \
    s += __shfl_xor(s, 16, 32);                                           \
    const float e = __expf(s + bs);                                       \
    if (c == 0) ev[(p) * 2 + h] = e;                                      \
    Z += e;                                                               \
    acc[0].x += e * buf[0].x; acc[0].y += e * buf[0].y;                   \
    acc[0].z += e * buf[0].z; acc[0].w += e * buf[0].w;                   \
    acc[1].x += e * buf[1].x; acc[1].y += e * buf[1].y;                   \
    acc[1].z += e * buf[1].z; acc[1].w += e * buf[1].w;                   \
    acc[2].x += e * buf[2].x; acc[2].y += e * buf[2].y;                   \
    acc[2].z += e * buf[2].z; acc[2].w += e * buf[2].w;                   \
    acc[3].x += e * buf[3].x; acc[3].y += e * buf[3].y;                   \
    acc[3].z += e * buf[3].z; acc[3].w += e * buf[3].w;                   \
  }

  // depth-3 rotating pipeline: two LD batches in flight ahead of each PROC
  LD(0, A);
  LD(1, Bf);
#pragma unroll
  for (int p = 0; p < PASSES; p += 3) {
    if (p + 2 < PASSES) LD(p + 2, Cf);
    PROC(p, A);
    if (p + 3 < PASSES) LD(p + 3, A);
    if (p + 1 < PASSES) PROC(p + 1, Bf);
    if (p + 4 < PASSES) LD(p + 4, Bf);
    if (p + 2 < PASSES) PROC(p + 2, Cf);
  }
#undef LD
#undef PROC

  // combine the two half-waves (lanes l and l^32 hold the same column slice)
#pragma unroll
  for (int k = 0; k < 4; ++k) {
    acc[k].x += __shfl_xor(acc[k].x, 32);
    acc[k].y += __shfl_xor(acc[k].y, 32);
    acc[k].z += __shfl_xor(acc[k].z, 32);
    acc[k].w += __shfl_xor(acc[k].w, 32);
  }
  Z += __shfl_xor(Z, 32);

  // per-wave partial -> LDS, block combine -> one partial record + compact Z
  __shared__ float4 sacc[4][128];  // 8 KB
  __shared__ float sZ[4];
  if (lane < 32) {
    sacc[wid][c]      = acc[0];
    sacc[wid][c + 32] = acc[1];
    sacc[wid][c + 64] = acc[2];
    sacc[wid][c + 96] = acc[3];
  }
  if (lane == 0) sZ[wid] = Z;
  __syncthreads();

  if (threadIdx.x < 128) {
    const int col = threadIdx.x;
    const float4 r0 = sacc[0][col], r1 = sacc[1][col];
    const float4 r2 = sacc[2][col], r3 = sacc[3][col];
    float4 r;
    r.x = (r0.x + r1.x) + (r2.x + r3.x);
    r.y = (r0.y + r1.y) + (r2.y + r3.y);
    r.z = (r0.z + r1.z) + (r2.z + r3.z);
    r.w = (r0.w + r1.w) + (r2.w + r3.w);
    reinterpret_cast<float4*>(partials + (size_t)blockIdx.x * PREC)[col] = r;
    if (col == 0) zarr[blockIdx.x] = (sZ[0] + sZ[1]) + (sZ[2] + sZ[3]);
  }
}

// ---------------------------------------------------------------------------
// Pass 2 (tiny, 2 blocks per batch): slice 0 merges the NC acc-partials ->
// outputs[b,:]; slice 1 normalizes staged e -> attention weights. Z comes
// from two contiguous cachelines per batch.
// ---------------------------------------------------------------------------
__global__ __launch_bounds__(512) void finalize_kernel(
    const float* __restrict__ partials, const float* __restrict__ zarr,
    float* __restrict__ weights, float* __restrict__ out) {
  const int b     = blockIdx.x >> 1;
  const int slice = blockIdx.x & 1;
  const int tid   = threadIdx.x;

  const float* zb = zarr + b * NC;
  float Zg = 0.f;
#pragma unroll
  for (int cc = 0; cc < NC; ++cc) Zg += zb[cc];
  const float invZ = 1.f / Zg;

  if (slice == 0) {
    // outputs: 128 float4 columns x 4 partial-groups, LDS tree
    const float* pb = partials + (size_t)b * NC * PREC;
    const int col = tid & 127;
    const int g   = tid >> 7;  // 0..3 -> records g, g+4, ...
    float4 r = make_float4(0.f, 0.f, 0.f, 0.f);
#pragma unroll
    for (int cc = g; cc < NC; cc += 4) {
      const float4 a = reinterpret_cast<const float4*>(pb + cc * PREC)[col];
      r.x += a.x; r.y += a.y; r.z += a.z; r.w += a.w;
    }
    __shared__ float4 red[512];
    red[tid] = r;
    __syncthreads();
    if (tid < 128) {
      const float4 a0 = red[tid], a1 = red[tid + 128];
      const float4 a2 = red[tid + 256], a3 = red[tid + 384];
      float4 o;
      o.x = ((a0.x + a1.x) + (a2.x + a3.x)) * invZ;
      o.y = ((a0.y + a1.y) + (a2.y + a3.y)) * invZ;
      o.z = ((a0.z + a1.z) + (a2.z + a3.z)) * invZ;
      o.w = ((a0.w + a1.w) + (a2.w + a3.w)) * invZ;
      reinterpret_cast<float4*>(out + (size_t)b * HH)[tid] = o;
    }
  } else {
    // weights: w = e * invZ, one float4 per thread (512 x 4 = 2048 = TT)
    float4* wv = reinterpret_cast<float4*>(weights + (size_t)b * TT);
    float4 v = wv[tid];
    v.x *= invZ; v.y *= invZ; v.z *= invZ; v.w *= invZ;
    wv[tid] = v;
  }
}

extern "C" void kernel_launch(void* const* d_in, const int* in_sizes, int n_in,
                              void* d_out, int out_size, void* d_ws, size_t ws_size,
                              hipStream_t stream) {
  const float* in   = (const float*)d_in[0];  // [B,T,H]
  const float* W    = (const float*)d_in[1];  // [H,1]
  const float* bias = (const float*)d_in[2];  // [1]

  float* out      = (float*)d_out;   // outputs [B,H]
  float* weights  = out + BB * HH;   // attention_weights [B,T,1]

  float* partials = (float*)d_ws;                       // 1024*512*4 = 2 MB
  float* zarr     = partials + (size_t)BB * NC * PREC;  // 1024 floats

  pass1_kernel<<<BB * NC, 256, 0, stream>>>(in, W, bias, weights, partials, zarr);
  finalize_kernel<<<BB * 2, 512, 0, stream>>>(partials, zarr, weights, out);
}

// Round 9
// 28.993 us; speedup vs baseline: 5.8930x; 1.0071x over previous
//
#include <hip/hip_runtime.h>

// Problem constants: B=32, T=2048, H=512, f32 in/out.
#define BB 32
#define TT 2048
#define HH 512

#define NC 32                      // chunks per batch (measured best: R4/R8)
#define CHUNK (TT / NC)            // 64 rows per block
#define RPW (CHUNK / 4)            // 16 rows per wave
#define PASSES (RPW / 2)           // 8 (2 rows per pass, half-wave each)
#define PREC 512                   // floats per partial record (acc only)

__device__ __forceinline__ float dot4(float4 a, float4 b) {
  return a.x * b.x + a.y * b.y + a.z * b.z + a.w * b.w;
}

// ---------------------------------------------------------------------------
// Pass 1 (single read of the input). No-max softmax (scores ~ N(0,1); f32
// exp overflow-safe; softmax shift-invariant). Half-wave row layout: lane l
// -> row parity h=l>>5, float4 col c=l&31. Per pass (2 rows): 4 float4
// loads/lane, 16-FMA partial dot, 5-step butterfly in 32 lanes, exp, 16
// independent accum FMAs. Stores e=exp(s+b) to the weights buffer.
// Depth-4 rotating-buffer pipeline (3 LD batches = 12 loads in flight ahead
// of each PROC): R7->R8 showed depth 2->3 bought 1.1us; one more notch.
// VGPR ~118 stays under the 128 cap for 4 waves/SIMD.
// ---------------------------------------------------------------------------
__global__ __launch_bounds__(256) void pass1_kernel(
    const float* __restrict__ in, const float* __restrict__ W,
    const float* __restrict__ bias, float* __restrict__ weights,
    float* __restrict__ partials, float* __restrict__ zarr) {
  const int b    = blockIdx.x >> 5;             // / NC
  const int ch   = blockIdx.x & (NC - 1);
  const int wid  = threadIdx.x >> 6;            // 0..3
  const int lane = threadIdx.x & 63;
  const int h    = lane >> 5;                   // row parity within pass
  const int c    = lane & 31;                   // float4 column 0..31

  const float4* w4p = reinterpret_cast<const float4*>(W);
  const float4 w0 = w4p[c];
  const float4 w1 = w4p[c + 32];
  const float4 w2 = w4p[c + 64];
  const float4 w3 = w4p[c + 96];
  const float bs = bias[0];

  const int t0 = ch * CHUNK + wid * RPW;
  const float4* rowbase = reinterpret_cast<const float4*>(in) +
                          ((size_t)b * TT + t0) * (HH / 4);
  float* ev = weights + (size_t)b * TT + t0;  // e staged here

  float4 acc[4];
  acc[0] = acc[1] = acc[2] = acc[3] = make_float4(0.f, 0.f, 0.f, 0.f);
  float Z = 0.f;

  float4 A[4], Bf[4], Cf[4], Df[4];

#define LD(p, buf)                                                        \
  {                                                                       \
    const float4* rp = rowbase + (size_t)((p) * 2 + h) * (HH / 4) + c;    \
    buf[0] = rp[0];                                                       \
    buf[1] = rp[32];                                                      \
    buf[2] = rp[64];                                                      \
    buf[3] = rp[96];                                                      \
  }

#define PROC(p, buf)                                                      \
  {                                                                       \
    float s = dot4(buf[0], w0) + dot4(buf[1], w1) +                       \
              dot4(buf[2], w2) + dot4(buf[3], w3);                        \
    s += __shfl_xor(s, 1, 32);                                            \
    s += __shfl_xor(s, 2, 32);                                            \
    s += __shfl_xor(s, 4, 32);                                            \
    s += __shfl_xor(s, 8, 32);                                            \
    s += __shfl_xor(s, 16, 32);                                           \
    const float e = __expf(s + bs);                                       \
    if (c == 0) ev[(p) * 2 + h] = e;                                      \
    Z += e;                                                               \
    acc[0].x += e * buf[0].x; acc[0].y += e * buf[0].y;                   \
    acc[0].z += e * buf[0].z; acc[0].w += e * buf[0].w;                   \
    acc[1].x += e * buf[1].x; acc[1].y += e * buf[1].y;                   \
    acc[1].z += e * buf[1].z; acc[1].w += e * buf[1].w;                   \
    acc[2].x += e * buf[2].x; acc[2].y += e * buf[2].y;                   \
    acc[2].z += e * buf[2].z; acc[2].w += e * buf[2].w;                   \
    acc[3].x += e * buf[3].x; acc[3].y += e * buf[3].y;                   \
    acc[3].z += e * buf[3].z; acc[3].w += e * buf[3].w;                   \
  }

  // depth-4 rotating pipeline: three LD batches in flight ahead of each PROC
  LD(0, A);
  LD(1, Bf);
  LD(2, Cf);
#pragma unroll
  for (int p = 0; p < PASSES; p += 4) {
    if (p + 3 < PASSES) LD(p + 3, Df);
    PROC(p, A);
    if (p + 4 < PASSES) LD(p + 4, A);
    if (p + 1 < PASSES) PROC(p + 1, Bf);
    if (p + 5 < PASSES) LD(p + 5, Bf);
    if (p + 2 < PASSES) PROC(p + 2, Cf);
    if (p + 6 < PASSES) LD(p + 6, Cf);
    if (p + 3 < PASSES) PROC(p + 3, Df);
  }
#undef LD
#undef PROC

  // combine the two half-waves (lanes l and l^32 hold the same column slice)
#pragma unroll
  for (int k = 0; k < 4; ++k) {
    acc[k].x += __shfl_xor(acc[k].x, 32);
    acc[k].y += __shfl_xor(acc[k].y, 32);
    acc[k].z += __shfl_xor(acc[k].z, 32);
    acc[k].w += __shfl_xor(acc[k].w, 32);
  }
  Z += __shfl_xor(Z, 32);

  // per-wave partial -> LDS, block combine -> one partial record + compact Z
  __shared__ float4 sacc[4][128];  // 8 KB
  __shared__ float sZ[4];
  if (lane < 32) {
    sacc[wid][c]      = acc[0];
    sacc[wid][c + 32] = acc[1];
    sacc[wid][c + 64] = acc[2];
    sacc[wid][c + 96] = acc[3];
  }
  if (lane == 0) sZ[wid] = Z;
  __syncthreads();

  if (threadIdx.x < 128) {
    const int col = threadIdx.x;
    const float4 r0 = sacc[0][col], r1 = sacc[1][col];
    const float4 r2 = sacc[2][col], r3 = sacc[3][col];
    float4 r;
    r.x = (r0.x + r1.x) + (r2.x + r3.x);
    r.y = (r0.y + r1.y) + (r2.y + r3.y);
    r.z = (r0.z + r1.z) + (r2.z + r3.z);
    r.w = (r0.w + r1.w) + (r2.w + r3.w);
    reinterpret_cast<float4*>(partials + (size_t)blockIdx.x * PREC)[col] = r;
    if (col == 0) zarr[blockIdx.x] = (sZ[0] + sZ[1]) + (sZ[2] + sZ[3]);
  }
}

// ---------------------------------------------------------------------------
// Pass 2 (tiny, 2 blocks per batch): slice 0 merges the NC acc-partials ->
// outputs[b,:]; slice 1 normalizes staged e -> attention weights. Z comes
// from two contiguous cachelines per batch.
// ---------------------------------------------------------------------------
__global__ __launch_bounds__(512) void finalize_kernel(
    const float* __restrict__ partials, const float* __restrict__ zarr,
    float* __restrict__ weights, float* __restrict__ out) {
  const int b     = blockIdx.x >> 1;
  const int slice = blockIdx.x & 1;
  const int tid   = threadIdx.x;

  const float* zb = zarr + b * NC;
  float Zg = 0.f;
#pragma unroll
  for (int cc = 0; cc < NC; ++cc) Zg += zb[cc];
  const float invZ = 1.f / Zg;

  if (slice == 0) {
    // outputs: 128 float4 columns x 4 partial-groups, LDS tree
    const float* pb = partials + (size_t)b * NC * PREC;
    const int col = tid & 127;
    const int g   = tid >> 7;  // 0..3 -> records g, g+4, ...
    float4 r = make_float4(0.f, 0.f, 0.f, 0.f);
#pragma unroll
    for (int cc = g; cc < NC; cc += 4) {
      const float4 a = reinterpret_cast<const float4*>(pb + cc * PREC)[col];
      r.x += a.x; r.y += a.y; r.z += a.z; r.w += a.w;
    }
    __shared__ float4 red[512];
    red[tid] = r;
    __syncthreads();
    if (tid < 128) {
      const float4 a0 = red[tid], a1 = red[tid + 128];
      const float4 a2 = red[tid + 256], a3 = red[tid + 384];
      float4 o;
      o.x = ((a0.x + a1.x) + (a2.x + a3.x)) * invZ;
      o.y = ((a0.y + a1.y) + (a2.y + a3.y)) * invZ;
      o.z = ((a0.z + a1.z) + (a2.z + a3.z)) * invZ;
      o.w = ((a0.w + a1.w) + (a2.w + a3.w)) * invZ;
      reinterpret_cast<float4*>(out + (size_t)b * HH)[tid] = o;
    }
  } else {
    // weights: w = e * invZ, one float4 per thread (512 x 4 = 2048 = TT)
    float4* wv = reinterpret_cast<float4*>(weights + (size_t)b * TT);
    float4 v = wv[tid];
    v.x *= invZ; v.y *= invZ; v.z *= invZ; v.w *= invZ;
    wv[tid] = v;
  }
}

extern "C" void kernel_launch(void* const* d_in, const int* in_sizes, int n_in,
                              void* d_out, int out_size, void* d_ws, size_t ws_size,
                              hipStream_t stream) {
  const float* in   = (const float*)d_in[0];  // [B,T,H]
  const float* W    = (const float*)d_in[1];  // [H,1]
  const float* bias = (const float*)d_in[2];  // [1]

  float* out      = (float*)d_out;   // outputs [B,H]
  float* weights  = out + BB * HH;   // attention_weights [B,T,1]

  float* partials = (float*)d_ws;                       // 1024*512*4 = 2 MB
  float* zarr     = partials + (size_t)BB * NC * PREC;  // 1024 floats

  pass1_kernel<<<BB * NC, 256, 0, stream>>>(in, W, bias, weights, partials, zarr);
  finalize_kernel<<<BB * 2, 512, 0, stream>>>(partials, zarr, weights, out);
}